// Round 2
// baseline (2711.912 us; speedup 1.0000x reference)
//
#include <hip/hip_runtime.h>
#include <math.h>

// Mesh encoder: 4x (spiral conv + ELU + sparse pool) + final GEMM.
// VERTS = [65536, 16384, 4096, 1024, 256], SEQ=9, CH=[3,32,64,128,256], B=16.
//
// Activations are kept in [V][C][B=16] layout so the spiral gather of a
// vertex is CIN*16 contiguous floats (coalesced float4 staging into LDS),
// and each thread register-tiles 4 couts x BH batches.

#define SEQL 9

// x [16][65536][3] -> xT [65536][3][16]
__global__ __launch_bounds__(256)
void transpose_x0(const float* __restrict__ x, float* __restrict__ xT)
{
    const int f = blockIdx.x * 256 + threadIdx.x;   // 65536*48 total
    const int v = f / 48, rem = f % 48;
    const int c = rem / 16, b = rem % 16;
    xT[f] = x[((size_t)b * 65536 + v) * 3 + c];
}

// Fused spiral-conv + ELU + pool-scatter.
// Thread tid = e*CO_LANES + cl; handles edge e (of EPB in block), couts
// [cl*4, cl*4+4), batches [bh0, bh0+BH).
template<int CIN, int COUT, int BH, int EPB>
__global__ __launch_bounds__(256)
void conv_pool(const float* __restrict__ xT,   // [NV][CIN][16]
               const int* __restrict__ idx,    // [NV][9]
               const int* __restrict__ row,
               const int* __restrict__ col,
               const float* __restrict__ val,
               const float* __restrict__ W,    // [9*CIN][COUT]
               const float* __restrict__ bias, // [COUT]
               float* __restrict__ out,        // [NVOUT][COUT][16], zeroed
               int nnz)
{
    constexpr int CO_LANES = COUT / 4;
    static_assert(EPB * CO_LANES == 256, "block must be 256 threads");
    constexpr int ESTRIDE  = CIN * BH + 4;      // +16B pad vs bank conflicts
    constexpr int F4_PER_E = CIN * BH / 4;
    constexpr int TOT4     = EPB * F4_PER_E;
    constexpr int NIT      = (TOT4 + 255) / 256;

    __shared__ float xg[EPB * ESTRIDE];
    __shared__ int   s_col[EPB], s_row[EPB], s_vi[EPB];
    __shared__ float s_val[EPB];

    const int tid = threadIdx.x;
    const int e   = tid / CO_LANES;
    const int cl  = tid % CO_LANES;
    const int co0 = cl * 4;
    const int k0  = blockIdx.x * EPB;
    const int bh0 = blockIdx.y * BH;

    if (tid < EPB) {
        const int k = k0 + tid;
        s_col[tid] = col[k];
        s_row[tid] = row[k];
        s_val[tid] = val[k];
    }

    const float4 bv = *(const float4*)(bias + co0);
    const float  bi[4] = {bv.x, bv.y, bv.z, bv.w};
    float acc[BH][4];
#pragma unroll
    for (int b = 0; b < BH; ++b)
#pragma unroll
        for (int i = 0; i < 4; ++i) acc[b][i] = bi[i];

    for (int s = 0; s < SEQL; ++s) {
        if (tid < EPB) s_vi[tid] = idx[s_col[tid] * SEQL + s];
        __syncthreads();   // also: compute(s-1) done before restaging xg

        // stage xg[e][c][b] = xT[vi(e)][c][bh0+b], coalesced float4
#pragma unroll
        for (int it = 0; it < NIT; ++it) {
            const int f = tid + it * 256;
            if (TOT4 % 256 == 0 || f < TOT4) {
                const int fe = f / F4_PER_E, fr = f % F4_PER_E;
                const int c = fr / (BH / 4), q = fr % (BH / 4);
                const float4 vv = *(const float4*)(
                    xT + (size_t)s_vi[fe] * (CIN * 16) + c * 16 + bh0 + q * 4);
                *(float4*)(xg + fe * ESTRIDE + fr * 4) = vv;
            }
        }
        __syncthreads();

        const float* xge = xg + e * ESTRIDE;
        const float* Wp  = W + (size_t)s * CIN * COUT + co0;
#pragma unroll
        for (int c = 0; c < CIN; ++c) {
            const float4 w = *(const float4*)(Wp + (size_t)c * COUT);
            const float wa[4] = {w.x, w.y, w.z, w.w};
#pragma unroll
            for (int b4 = 0; b4 < BH / 4; ++b4) {
                const float4 xv = *(const float4*)(xge + c * BH + b4 * 4);
                const float xa[4] = {xv.x, xv.y, xv.z, xv.w};
#pragma unroll
                for (int bb = 0; bb < 4; ++bb)
#pragma unroll
                    for (int ii = 0; ii < 4; ++ii)
                        acc[b4 * 4 + bb][ii] =
                            fmaf(xa[bb], wa[ii], acc[b4 * 4 + bb][ii]);
            }
        }
    }

    const int   r = s_row[e];
    const float v = s_val[e];
    float* op = out + ((size_t)r * COUT + co0) * 16 + bh0;
#pragma unroll
    for (int i = 0; i < 4; ++i)
#pragma unroll
        for (int b = 0; b < BH; ++b) {
            float y = acc[b][i];
            y = (y > 0.0f) ? y : expm1f(y);
            atomicAdd(op + i * 16 + b, v * y);
        }
}

// Final GEMM partials: part[jblk][b][l] = sum_{j in blk} x4T[j][b]*Wf[j][l]
__global__ __launch_bounds__(256)
void final_gemm_partial(const float* __restrict__ x4T,  // [65536][16]
                        const float* __restrict__ Wf,   // [65536][256]
                        float* __restrict__ part)       // [256][16][256]
{
    __shared__ float xs[256 * 16];
    const int j0 = blockIdx.x * 256;
    const int t  = threadIdx.x;

#pragma unroll
    for (int it = 0; it < 4; ++it) {
        const int f = t + it * 256;
        *(float4*)(xs + f * 4) =
            *(const float4*)(x4T + (size_t)j0 * 16 + f * 4);
    }
    __syncthreads();

    float acc[16];
#pragma unroll
    for (int b = 0; b < 16; ++b) acc[b] = 0.0f;

#pragma unroll 4
    for (int jj = 0; jj < 256; ++jj) {
        const float w = Wf[(size_t)(j0 + jj) * 256 + t];
#pragma unroll
        for (int b4 = 0; b4 < 4; ++b4) {
            const float4 xv = *(const float4*)(xs + jj * 16 + b4 * 4);
            acc[b4 * 4 + 0] = fmaf(xv.x, w, acc[b4 * 4 + 0]);
            acc[b4 * 4 + 1] = fmaf(xv.y, w, acc[b4 * 4 + 1]);
            acc[b4 * 4 + 2] = fmaf(xv.z, w, acc[b4 * 4 + 2]);
            acc[b4 * 4 + 3] = fmaf(xv.w, w, acc[b4 * 4 + 3]);
        }
    }
#pragma unroll
    for (int b = 0; b < 16; ++b)
        part[(size_t)blockIdx.x * 4096 + b * 256 + t] = acc[b];
}

__global__ __launch_bounds__(256)
void final_reduce(const float* __restrict__ part, const float* __restrict__ bf,
                  float* __restrict__ out)
{
    const int b = blockIdx.x, l = threadIdx.x;   // 16 blocks x 256
    float s = 0.0f;
    for (int jb = 0; jb < 256; ++jb)
        s += part[(size_t)jb * 4096 + b * 256 + l];
    out[b * 256 + l] = s + bf[l];
}

extern "C" void kernel_launch(void* const* d_in, const int* in_sizes, int n_in,
                              void* d_out, int out_size, void* d_ws, size_t ws_size,
                              hipStream_t stream)
{
    const float* x    = (const float*)d_in[0];
    const int*   idx0 = (const int*)d_in[1];
    const int*   row0 = (const int*)d_in[2];
    const int*   col0 = (const int*)d_in[3];
    const float* val0 = (const float*)d_in[4];
    const float* W0   = (const float*)d_in[5];
    const float* b0   = (const float*)d_in[6];
    const int*   idx1 = (const int*)d_in[7];
    const int*   row1 = (const int*)d_in[8];
    const int*   col1 = (const int*)d_in[9];
    const float* val1 = (const float*)d_in[10];
    const float* W1   = (const float*)d_in[11];
    const float* b1   = (const float*)d_in[12];
    const int*   idx2 = (const int*)d_in[13];
    const int*   row2 = (const int*)d_in[14];
    const int*   col2 = (const int*)d_in[15];
    const float* val2 = (const float*)d_in[16];
    const float* W2   = (const float*)d_in[17];
    const float* b2   = (const float*)d_in[18];
    const int*   idx3 = (const int*)d_in[19];
    const int*   row3 = (const int*)d_in[20];
    const int*   col3 = (const int*)d_in[21];
    const float* val3 = (const float*)d_in[22];
    const float* W3   = (const float*)d_in[23];
    const float* b3   = (const float*)d_in[24];
    const float* Wf   = (const float*)d_in[25];
    const float* bf   = (const float*)d_in[26];

    float* ws  = (float*)d_ws;
    float* A   = ws;                 // xT0: 65536*48       = 3,145,728 f
    float* C   = ws;                 // x2T: 4096*64*16     = 4,194,304 f (A dead)
    float* B   = ws + 4194304;       // x1T: 16384*32*16    = 8,388,608 f
    float* D   = ws + 4194304;       // x3T: 1024*128*16    = 2,097,152 f (B dead)
    float* E   = ws;                 // x4T: 256*256*16     = 1,048,576 f (C dead)
    float* F   = ws + 1048576;       // partials: 256*4096  = 1,048,576 f
    float* out = (float*)d_out;

    // x -> xT0
    transpose_x0<<<12288, 256, 0, stream>>>(x, A);

    // L0: xT0 -> x1T [16384][32][16]; nnz=49152
    hipMemsetAsync(B, 0, (size_t)8388608 * 4, stream);
    conv_pool<3, 32, 16, 32><<<dim3(49152 / 32, 1), 256, 0, stream>>>(
        A, idx0, row0, col0, val0, W0, b0, B, 49152);

    // L1: x1T -> x2T [4096][64][16]; nnz=12288
    hipMemsetAsync(C, 0, (size_t)4194304 * 4, stream);
    conv_pool<32, 64, 16, 16><<<dim3(12288 / 16, 1), 256, 0, stream>>>(
        B, idx1, row1, col1, val1, W1, b1, C, 12288);

    // L2: x2T -> x3T [1024][128][16]; nnz=3072
    hipMemsetAsync(D, 0, (size_t)2097152 * 4, stream);
    conv_pool<64, 128, 8, 8><<<dim3(3072 / 8, 2), 256, 0, stream>>>(
        C, idx2, row2, col2, val2, W2, b2, D, 3072);

    // L3: x3T -> x4T [256][256][16]; nnz=768
    hipMemsetAsync(E, 0, (size_t)1048576 * 4, stream);
    conv_pool<128, 256, 4, 4><<<dim3(768 / 4, 4), 256, 0, stream>>>(
        D, idx3, row3, col3, val3, W3, b3, E, 768);

    // Final GEMM: out[16,256] = bf + x4_flat @ Wf
    final_gemm_partial<<<256, 256, 0, stream>>>(E, Wf, F);
    final_reduce<<<16, 256, 0, stream>>>(F, bf, out);
}